// Round 4
// baseline (3580.352 us; speedup 1.0000x reference)
//
#include <hip/hip_runtime.h>
#include <math.h>

#define TT 2048
#define UU 64
#define BB 256

// Fast activations on v_exp_f32 / v_rcp_f32 (~1e-7 abs err; threshold 3.45e-6;
// validated at absmax 9.5e-7 in rounds 2/3).
__device__ __forceinline__ float frcp(float x) { return __builtin_amdgcn_rcpf(x); }
__device__ __forceinline__ float fsigmoid(float x) { return frcp(1.0f + __expf(-x)); }
__device__ __forceinline__ float ftanh(float x) { return 1.0f - 2.0f * frcp(1.0f + __expf(2.0f * x)); }

// One wave (64 threads) per batch element, 256 blocks = 1 per CU.
// Round-2 structure (it passed; its only flaw was the spilled weight array ->
// VGPR_Count 152 + scratch traffic). Thread u owns unit u and ALL FOUR gate
// columns of W0 held in 64 NAMED float4 registers (256 VGPRs; named scalars
// are SROA-promoted — rounds 1/2 proved arrays are not). Per step:
//   16 ds_read_b128 broadcasts of h (DS ~190 cyc, 4x less than the 4-wave
//   variant), 256 FMAs, NO barriers, NO z-exchange (all 4 gates of unit u in
//   lane u). Layer-1 (1 unit) lagged one step: butterfly-reduce hprev.W1 (24
//   ds_swizzle, overlaps the h broadcasts on the DS pipe), replicated (c1,h1)
//   update, output banked per-lane and flushed coalesced every 64 steps.
// DS ops within a wave execute in order -> h write then broadcast read needs
// no fence beyond lgkmcnt, which the compiler inserts.
__global__ __launch_bounds__(64, 1) void lstm_ts_kernel(
    const float* __restrict__ x, const float* __restrict__ W0,
    const float* __restrict__ b0, const float* __restrict__ W1,
    const float* __restrict__ b1, const float* __restrict__ Wd,
    const float* __restrict__ bd, float* __restrict__ out)
{
    __shared__ float xbuf[TT];
    __shared__ __align__(16) float hbuf[UU];

    const int u = threadIdx.x;
    const int b = blockIdx.x;
    const float* xrow = x + b * TT;
    float* outrow = out + b * TT;

    // ---- prologue: stage x, sum of squares over T (in-wave) ----
    float ss = 0.f;
    #pragma unroll 4
    for (int i = 0; i < TT / 64; ++i) {
        float v = xrow[u + i * 64];
        xbuf[u + i * 64] = v;
        ss += v * v;
    }
    #pragma unroll
    for (int m = 1; m < 64; m <<= 1) ss += __shfl_xor(ss, m, 64);
    const float scale = 1.0f / sqrtf(fmaxf(ss, 1e-12f));  // precise, once

    // ---- weights: 64 NAMED float4 (256 VGPRs). Wk{k}.g = W0[(1+k)][g*64+u] ----
    #define DECLW(k) float4 Wk##k; \
        Wk##k.x = W0[(1 + k) * 256 +       u]; \
        Wk##k.y = W0[(1 + k) * 256 +  64 + u]; \
        Wk##k.z = W0[(1 + k) * 256 + 128 + u]; \
        Wk##k.w = W0[(1 + k) * 256 + 192 + u];
    DECLW(0)  DECLW(1)  DECLW(2)  DECLW(3)  DECLW(4)  DECLW(5)  DECLW(6)  DECLW(7)
    DECLW(8)  DECLW(9)  DECLW(10) DECLW(11) DECLW(12) DECLW(13) DECLW(14) DECLW(15)
    DECLW(16) DECLW(17) DECLW(18) DECLW(19) DECLW(20) DECLW(21) DECLW(22) DECLW(23)
    DECLW(24) DECLW(25) DECLW(26) DECLW(27) DECLW(28) DECLW(29) DECLW(30) DECLW(31)
    DECLW(32) DECLW(33) DECLW(34) DECLW(35) DECLW(36) DECLW(37) DECLW(38) DECLW(39)
    DECLW(40) DECLW(41) DECLW(42) DECLW(43) DECLW(44) DECLW(45) DECLW(46) DECLW(47)
    DECLW(48) DECLW(49) DECLW(50) DECLW(51) DECLW(52) DECLW(53) DECLW(54) DECLW(55)
    DECLW(56) DECLW(57) DECLW(58) DECLW(59) DECLW(60) DECLW(61) DECLW(62) DECLW(63)
    #undef DECLW

    // input weights (l2-norm scale folded) and biases — named scalars
    const float wxs0 = W0[u] * scale,        wxs1 = W0[64 + u] * scale;
    const float wxs2 = W0[128 + u] * scale,  wxs3 = W0[192 + u] * scale;
    const float bc0 = b0[u],       bc1 = b0[64 + u];
    const float bc2 = b0[128 + u], bc3 = b0[192 + u];
    const float w1v0 = W1[u * 4 + 0], w1v1 = W1[u * 4 + 1];
    const float w1v2 = W1[u * 4 + 2], w1v3 = W1[u * 4 + 3];
    const float w1h0 = W1[256], w1h1 = W1[257], w1h2 = W1[258], w1h3 = W1[259];
    const float b10 = b1[0], b11 = b1[1], b12 = b1[2], b13 = b1[3];
    const float wd = Wd[0], bdv = bd[0];

    hbuf[u] = 0.f;
    float c0 = 0.f, hprev = 0.f;
    float c1 = 0.f, h1 = 0.f;
    float oval = 0.f;
    __syncthreads();  // single wave; outside loop

    const float4* hv4 = reinterpret_cast<const float4*>(hbuf);

    for (int t = 0; t < TT; ++t) {
        // ---- 16 broadcast b128 reads of h into named regs ----
        #define DECLH(i) const float4 h4_##i = hv4[i];
        DECLH(0)  DECLH(1)  DECLH(2)  DECLH(3)
        DECLH(4)  DECLH(5)  DECLH(6)  DECLH(7)
        DECLH(8)  DECLH(9)  DECLH(10) DECLH(11)
        DECLH(12) DECLH(13) DECLH(14) DECLH(15)
        #undef DECLH

        // ---- layer-1 for step t-1 (lagged; independent of this step's matvec,
        //      its swizzles share the DS pipe with the h broadcasts) ----
        if (t > 0) {
            float p0 = hprev * w1v0, p1 = hprev * w1v1;
            float p2 = hprev * w1v2, p3 = hprev * w1v3;
            #pragma unroll
            for (int m = 1; m < 64; m <<= 1) {
                p0 += __shfl_xor(p0, m, 64);
                p1 += __shfl_xor(p1, m, 64);
                p2 += __shfl_xor(p2, m, 64);
                p3 += __shfl_xor(p3, m, 64);
            }
            const float z1i = p0 + fmaf(h1, w1h0, b10);
            const float z1j = p1 + fmaf(h1, w1h1, b11);
            const float z1f = p2 + fmaf(h1, w1h2, b12);
            const float z1o = p3 + fmaf(h1, w1h3, b13);
            c1 = fsigmoid(z1f + 1.0f) * c1 + fsigmoid(z1i) * ftanh(z1j);
            h1 = fsigmoid(z1o) * ftanh(c1);
            const int s = t - 1;
            const float ov = fmaf(h1, wd, bdv);
            if ((s & 63) == u) oval = ov;                       // bank in lane s&63
            if ((s & 63) == 63) outrow[(s & ~63) + u] = oval;   // coalesced flush
        }

        // ---- layer-0 matvec: 256 FMAs, 4 gate-accumulators x 4 chains ----
        float4 zv0 = {0.f, 0.f, 0.f, 0.f}, zv1 = {0.f, 0.f, 0.f, 0.f};
        float4 zv2 = {0.f, 0.f, 0.f, 0.f}, zv3 = {0.f, 0.f, 0.f, 0.f};
        #define FMA4(acc, s, W) \
            acc.x = fmaf(s, W.x, acc.x); acc.y = fmaf(s, W.y, acc.y); \
            acc.z = fmaf(s, W.z, acc.z); acc.w = fmaf(s, W.w, acc.w);
        #define STEP4(i, A, B, C, D) { \
            FMA4(zv0, h4_##i.x, Wk##A) FMA4(zv1, h4_##i.y, Wk##B) \
            FMA4(zv2, h4_##i.z, Wk##C) FMA4(zv3, h4_##i.w, Wk##D) }
        STEP4(0,  0,  1,  2,  3)   STEP4(1,  4,  5,  6,  7)
        STEP4(2,  8,  9,  10, 11)  STEP4(3,  12, 13, 14, 15)
        STEP4(4,  16, 17, 18, 19)  STEP4(5,  20, 21, 22, 23)
        STEP4(6,  24, 25, 26, 27)  STEP4(7,  28, 29, 30, 31)
        STEP4(8,  32, 33, 34, 35)  STEP4(9,  36, 37, 38, 39)
        STEP4(10, 40, 41, 42, 43)  STEP4(11, 44, 45, 46, 47)
        STEP4(12, 48, 49, 50, 51)  STEP4(13, 52, 53, 54, 55)
        STEP4(14, 56, 57, 58, 59)  STEP4(15, 60, 61, 62, 63)
        #undef STEP4
        #undef FMA4

        const float xr = xbuf[t];
        const float zi = ((zv0.x + zv1.x) + (zv2.x + zv3.x)) + fmaf(xr, wxs0, bc0);
        const float zj = ((zv0.y + zv1.y) + (zv2.y + zv3.y)) + fmaf(xr, wxs1, bc1);
        const float zf = ((zv0.z + zv1.z) + (zv2.z + zv3.z)) + fmaf(xr, wxs2, bc2);
        const float zo = ((zv0.w + zv1.w) + (zv2.w + zv3.w)) + fmaf(xr, wxs3, bc3);

        // ---- layer-0 cell update for unit u ----
        c0 = fsigmoid(zf + 1.0f) * c0 + fsigmoid(zi) * ftanh(zj);
        const float h = fsigmoid(zo) * ftanh(c0);
        hprev = h;
        hbuf[u] = h;  // in-wave DS ordering; no barrier
    }

    // ---- epilogue: layer-1 for s = TT-1, flush last 64 outputs ----
    {
        float p0 = hprev * w1v0, p1 = hprev * w1v1;
        float p2 = hprev * w1v2, p3 = hprev * w1v3;
        #pragma unroll
        for (int m = 1; m < 64; m <<= 1) {
            p0 += __shfl_xor(p0, m, 64);
            p1 += __shfl_xor(p1, m, 64);
            p2 += __shfl_xor(p2, m, 64);
            p3 += __shfl_xor(p3, m, 64);
        }
        const float z1i = p0 + fmaf(h1, w1h0, b10);
        const float z1j = p1 + fmaf(h1, w1h1, b11);
        const float z1f = p2 + fmaf(h1, w1h2, b12);
        const float z1o = p3 + fmaf(h1, w1h3, b13);
        c1 = fsigmoid(z1f + 1.0f) * c1 + fsigmoid(z1i) * ftanh(z1j);
        h1 = fsigmoid(z1o) * ftanh(c1);
        if (u == 63) oval = fmaf(h1, wd, bdv);
        outrow[TT - 64 + u] = oval;
    }
}

extern "C" void kernel_launch(void* const* d_in, const int* in_sizes, int n_in,
                              void* d_out, int out_size, void* d_ws, size_t ws_size,
                              hipStream_t stream) {
    const float* x  = (const float*)d_in[0];
    const float* W0 = (const float*)d_in[1];
    const float* b0 = (const float*)d_in[2];
    const float* W1 = (const float*)d_in[3];
    const float* b1 = (const float*)d_in[4];
    const float* Wd = (const float*)d_in[5];
    const float* bd = (const float*)d_in[6];
    float* out = (float*)d_out;
    lstm_ts_kernel<<<BB, 64, 0, stream>>>(x, W0, b0, W1, b1, Wd, bd, out);
}

// Round 5
// 1269.434 us; speedup vs baseline: 2.8204x; 2.8204x over previous
//
#include <hip/hip_runtime.h>
#include <math.h>

#define TT 2048
#define UU 64
#define BB 256
#define NTHR 320   // 5 waves: 4 producers (one per gate) + 1 layer-1 consumer

// Fast activations on v_exp_f32 / v_rcp_f32 (~1e-7 abs err; threshold 3.45e-6;
// validated at absmax 9.5e-7 in rounds 2-4).
__device__ __forceinline__ float frcp(float x) { return __builtin_amdgcn_rcpf(x); }
__device__ __forceinline__ float fsigmoid(float x) { return frcp(1.0f + __expf(-x)); }
__device__ __forceinline__ float ftanh(float x) { return 1.0f - 2.0f * frcp(1.0f + __expf(2.0f * x)); }

// Opaque pin: blocks LLVM from rematerializing the weight loads inside the
// loop (round 3 evidence: VGPR_Count=64 -> weights were re-loaded from L2
// every step instead of staying register-resident).
#define PIN(v) asm volatile("" : "+v"(v))

// One block per batch element (256 blocks = 1/CU), 320 threads = 5 waves.
// Waves 0-3 (producers): wave g, lane u owns W0 column c=g*64+u (64 floats,
//   pinned in VGPRs). h[u] lives in a REGISTER in every producer wave
//   (redundant post-barrier update) -> matvec broadcasts h via v_readlane
//   (no LDS round-trip). Per step: 64 readlane+FMA -> z_c -> zbuf -> ONE
//   barrier -> read 4 z's (2x ds_read2) -> activations -> h. Wave 0 also
//   writes h into a depth-2 LDS ring for the consumer.
// Wave 4 (consumer): lagged one step behind. After barrier #t it reads
//   ring[(t-1)&1] (written before barrier #t -> visible; overwritten only
//   after barrier #t+2 -> race-free), butterfly-reduces h.W1, updates
//   (c1,h1), banks the dense output per-lane, flushes coalesced every 64
//   steps. All its work overlaps the producers' post-barrier phase.
// All 5 waves execute exactly 2050 barriers -> no deadlock.
__global__ __launch_bounds__(NTHR, 1) void lstm_ts_kernel(
    const float* __restrict__ x, const float* __restrict__ W0,
    const float* __restrict__ b0, const float* __restrict__ W1,
    const float* __restrict__ b1, const float* __restrict__ Wd,
    const float* __restrict__ bd, float* __restrict__ out)
{
    __shared__ float xbuf[TT];
    __shared__ float zbuf[2][256];
    __shared__ float ring[2][UU];
    __shared__ float red[5];

    const int tid = threadIdx.x;
    const int wid = tid >> 6;
    const int u = tid & 63;
    const int b = blockIdx.x;
    const float* xrow = x + b * TT;
    float* outrow = out + b * TT;

    // ---- prologue: stage x, sum of squares over T (all 5 waves) ----
    float ss = 0.f;
    for (int i = tid; i < TT; i += NTHR) {
        float v = xrow[i];
        xbuf[i] = v;
        ss += v * v;
    }
    #pragma unroll
    for (int m = 1; m < 64; m <<= 1) ss += __shfl_xor(ss, m, 64);
    if (u == 0) red[wid] = ss;
    __syncthreads();  // B0

    if (wid < 4) {
        // ================= PRODUCER: gate g = wid =================
        const int g = wid;
        const int c = g * 64 + u;  // owned W0 column
        const float sq = ((red[0] + red[1]) + (red[2] + red[3])) + red[4];
        const float scale = 1.0f / sqrtf(fmaxf(sq, 1e-12f));  // precise, once

        // 16 named float4 = 64 weight VGPRs, pinned against remat
        #define DECLW(i) float4 Wk##i; \
            Wk##i.x = W0[(1 + 4*i + 0) * 256 + c]; \
            Wk##i.y = W0[(1 + 4*i + 1) * 256 + c]; \
            Wk##i.z = W0[(1 + 4*i + 2) * 256 + c]; \
            Wk##i.w = W0[(1 + 4*i + 3) * 256 + c]; \
            PIN(Wk##i.x); PIN(Wk##i.y); PIN(Wk##i.z); PIN(Wk##i.w);
        DECLW(0)  DECLW(1)  DECLW(2)  DECLW(3)
        DECLW(4)  DECLW(5)  DECLW(6)  DECLW(7)
        DECLW(8)  DECLW(9)  DECLW(10) DECLW(11)
        DECLW(12) DECLW(13) DECLW(14) DECLW(15)
        #undef DECLW

        const float wxs = W0[c] * scale;  // l2-norm scale folded in
        const float bc  = b0[c];

        float c0 = 0.f, h = 0.f;

        for (int t = 0; t < TT; ++t) {
            const int p = t & 1;
            const float xr = xbuf[t];
            const int hi = __float_as_int(h);

            // ---- matvec: broadcast h_k via readlane, 4 acc chains ----
            float a0 = 0.f, a1 = 0.f, a2 = 0.f, a3 = 0.f;
            #define MAC4(i) \
                a0 = fmaf(__int_as_float(__builtin_amdgcn_readlane(hi, 4*i+0)), Wk##i.x, a0); \
                a1 = fmaf(__int_as_float(__builtin_amdgcn_readlane(hi, 4*i+1)), Wk##i.y, a1); \
                a2 = fmaf(__int_as_float(__builtin_amdgcn_readlane(hi, 4*i+2)), Wk##i.z, a2); \
                a3 = fmaf(__int_as_float(__builtin_amdgcn_readlane(hi, 4*i+3)), Wk##i.w, a3);
            MAC4(0)  MAC4(1)  MAC4(2)  MAC4(3)
            MAC4(4)  MAC4(5)  MAC4(6)  MAC4(7)
            MAC4(8)  MAC4(9)  MAC4(10) MAC4(11)
            MAC4(12) MAC4(13) MAC4(14) MAC4(15)
            #undef MAC4

            zbuf[p][c] = ((a0 + a1) + (a2 + a3)) + fmaf(xr, wxs, bc);
            __syncthreads();  // B(t+1)

            // ---- redundant unit update (keeps h in regs in all 4 waves) ----
            const float zi = zbuf[p][u];
            const float zj = zbuf[p][64 + u];
            const float zf = zbuf[p][128 + u];
            const float zo = zbuf[p][192 + u];
            c0 = fsigmoid(zf + 1.0f) * c0 + fsigmoid(zi) * ftanh(zj);
            h = fsigmoid(zo) * ftanh(c0);
            if (g == 0) ring[p][u] = h;  // for the consumer wave
        }
        __syncthreads();  // B(TT+1)
    } else {
        // ================= CONSUMER: layer 1 + dense + store =================
        const float w1v0 = W1[u * 4 + 0], w1v1 = W1[u * 4 + 1];
        const float w1v2 = W1[u * 4 + 2], w1v3 = W1[u * 4 + 3];
        const float w1h0 = W1[256], w1h1 = W1[257], w1h2 = W1[258], w1h3 = W1[259];
        const float b10 = b1[0], b11 = b1[1], b12 = b1[2], b13 = b1[3];
        const float wd = Wd[0], bdv = bd[0];

        float c1 = 0.f, h1 = 0.f, oval = 0.f;

        #define L1STEP(s) { \
            const float hu = ring[(s) & 1][u]; \
            float p0 = hu * w1v0, p1 = hu * w1v1, p2 = hu * w1v2, p3 = hu * w1v3; \
            _Pragma("unroll") \
            for (int m = 1; m < 64; m <<= 1) { \
                p0 += __shfl_xor(p0, m, 64); \
                p1 += __shfl_xor(p1, m, 64); \
                p2 += __shfl_xor(p2, m, 64); \
                p3 += __shfl_xor(p3, m, 64); \
            } \
            const float z1i = p0 + fmaf(h1, w1h0, b10); \
            const float z1j = p1 + fmaf(h1, w1h1, b11); \
            const float z1f = p2 + fmaf(h1, w1h2, b12); \
            const float z1o = p3 + fmaf(h1, w1h3, b13); \
            c1 = fsigmoid(z1f + 1.0f) * c1 + fsigmoid(z1i) * ftanh(z1j); \
            h1 = fsigmoid(z1o) * ftanh(c1); \
            const float ov = fmaf(h1, wd, bdv); \
            if (((s) & 63) == u) oval = ov; \
            if (((s) & 63) == 63) outrow[((s) & ~63) + u] = oval; \
        }

        for (int t = 0; t < TT; ++t) {
            __syncthreads();  // B(t+1)
            if (t > 0) L1STEP(t - 1)
        }
        __syncthreads();  // B(TT+1) — makes ring[(TT-1)&1] visible
        L1STEP(TT - 1)
        #undef L1STEP
    }
}

extern "C" void kernel_launch(void* const* d_in, const int* in_sizes, int n_in,
                              void* d_out, int out_size, void* d_ws, size_t ws_size,
                              hipStream_t stream) {
    const float* x  = (const float*)d_in[0];
    const float* W0 = (const float*)d_in[1];
    const float* b0 = (const float*)d_in[2];
    const float* W1 = (const float*)d_in[3];
    const float* b1 = (const float*)d_in[4];
    const float* Wd = (const float*)d_in[5];
    const float* bd = (const float*)d_in[6];
    float* out = (float*)d_out;
    lstm_ts_kernel<<<BB, NTHR, 0, stream>>>(x, W0, b0, W1, b1, Wd, bd, out);
}